// Round 5
// baseline (1202.173 us; speedup 1.0000x reference)
//
#include <hip/hip_runtime.h>

#define IN_F 128
#define OUT_F 64
typedef unsigned int u32;

// ---------------------------------------------------------------------------
// Kernel 1: sp = x @ W. 64x64 tile per block (256 thr), 4 rows x 4 cols per
// thread -> 128B LDS per 64 FMA (vs 80B/16 before). W in LDS [k][j], x rows
// padded stride 132 (rows 8 apart alias same banks = 2-way = free).
// ---------------------------------------------------------------------------
__global__ __launch_bounds__(256, 2) void gemm_xw(
    const float* __restrict__ x, const float* __restrict__ W,
    float* __restrict__ sp, int n_nodes)
{
    __shared__ float Wlds[IN_F * OUT_F];     // 32 KB
    __shared__ float xlds[64][IN_F + 4];     // 33.8 KB, stride 132

    const int t = threadIdx.x;
    const int row0 = blockIdx.x * 64;

    // W: 8192 floats, 8 float4/thread, perfectly coalesced, linear LDS.
    #pragma unroll
    for (int j = 0; j < 8; ++j) {
        const int off = j * 1024 + t * 4;
        *(float4*)&Wlds[off] = *(const float4*)&W[off];
    }
    // x tile: 64 rows x 128 = 8192 floats contiguous at x + row0*128.
    #pragma unroll
    for (int j = 0; j < 8; ++j) {
        const int off = j * 1024 + t * 4;     // float index in tile
        const int r = off >> 7, k = off & 127;
        if (row0 + r < n_nodes)
            *(float4*)&xlds[r][k] = *(const float4*)&x[(size_t)row0 * IN_F + off];
    }
    __syncthreads();

    const int ty = t >> 4;          // 0..15 -> rows ty*4..ty*4+3
    const int tx = (t & 15) * 4;    // feature group

    float4 acc0 = {0,0,0,0}, acc1 = {0,0,0,0}, acc2 = {0,0,0,0}, acc3 = {0,0,0,0};

    #pragma unroll
    for (int k = 0; k < IN_F; k += 4) {
        float4 w0 = *(float4*)&Wlds[(k + 0) * OUT_F + tx];
        float4 w1 = *(float4*)&Wlds[(k + 1) * OUT_F + tx];
        float4 w2 = *(float4*)&Wlds[(k + 2) * OUT_F + tx];
        float4 w3 = *(float4*)&Wlds[(k + 3) * OUT_F + tx];
        #pragma unroll
        for (int i = 0; i < 4; ++i) {
            float4 xv = *(float4*)&xlds[ty * 4 + i][k];
            float4* a = (i == 0) ? &acc0 : (i == 1) ? &acc1 : (i == 2) ? &acc2 : &acc3;
            a->x += xv.x * w0.x + xv.y * w1.x + xv.z * w2.x + xv.w * w3.x;
            a->y += xv.x * w0.y + xv.y * w1.y + xv.z * w2.y + xv.w * w3.y;
            a->z += xv.x * w0.z + xv.y * w1.z + xv.z * w2.z + xv.w * w3.z;
            a->w += xv.x * w0.w + xv.y * w1.w + xv.z * w2.w + xv.w * w3.w;
        }
    }
    #pragma unroll
    for (int i = 0; i < 4; ++i) {
        const int row = row0 + ty * 4 + i;
        if (row < n_nodes) {
            float4 a = (i == 0) ? acc0 : (i == 1) ? acc1 : (i == 2) ? acc2 : acc3;
            *(float4*)&sp[(size_t)row * OUT_F + tx] = a;
        }
    }
}

// ---------------------------------------------------------------------------
// Counting sort of edges by row: hist -> scan (3 kernels) -> scatter.
// ---------------------------------------------------------------------------
__global__ __launch_bounds__(256) void hist_rows(
    const int* __restrict__ rows, u32* __restrict__ counts, int n_edges)
{
    const int e = blockIdx.x * 256 + threadIdx.x;
    if (e < n_edges) atomicAdd(&counts[rows[e]], 1u);
}

// scan1: per-block (2048 elems) exclusive partials + block sums
__global__ __launch_bounds__(256) void scan1(
    const u32* __restrict__ counts, u32* __restrict__ partial,
    u32* __restrict__ blockSums, int n)
{
    __shared__ u32 sdata[256];
    const int t = threadIdx.x;
    const int base = blockIdx.x * 2048 + t * 8;
    u32 v[8], s = 0;
    #pragma unroll
    for (int j = 0; j < 8; ++j) { v[j] = (base + j < n) ? counts[base + j] : 0u; s += v[j]; }
    sdata[t] = s;
    __syncthreads();
    for (int off = 1; off < 256; off <<= 1) {
        u32 xv = (t >= off) ? sdata[t - off] : 0u;
        __syncthreads();
        sdata[t] += xv;
        __syncthreads();
    }
    const u32 excl = sdata[t] - s;
    if (t == 255) blockSums[blockIdx.x] = sdata[255];
    u32 run = excl;
    #pragma unroll
    for (int j = 0; j < 8; ++j) { if (base + j < n) partial[base + j] = run; run += v[j]; }
}

// scan2: single block, exclusive scan of block sums (in place)
__global__ __launch_bounds__(256) void scan2(u32* __restrict__ blockSums, int nb)
{
    __shared__ u32 sdata[256];
    const int t = threadIdx.x;
    const u32 v = (t < nb) ? blockSums[t] : 0u;
    sdata[t] = v;
    __syncthreads();
    for (int off = 1; off < 256; off <<= 1) {
        u32 xv = (t >= off) ? sdata[t - off] : 0u;
        __syncthreads();
        sdata[t] += xv;
        __syncthreads();
    }
    if (t < nb) blockSums[t] = sdata[t] - v;
}

// scan3: add block offsets; produce final offsets + cursor copy; offsets[n]=E
__global__ __launch_bounds__(256) void scan3(
    u32* __restrict__ offsets, const u32* __restrict__ blockSums,
    u32* __restrict__ cursors, int n, int total)
{
    const int i = blockIdx.x * 256 + threadIdx.x;
    if (i < n) {
        const u32 o = offsets[i] + blockSums[i >> 11];
        offsets[i] = o;
        cursors[i] = o;
    }
    if (i == n) offsets[n] = (u32)total;
}

__global__ __launch_bounds__(256) void sort_scatter(
    const int* __restrict__ rows, const int* __restrict__ cols,
    const float* __restrict__ vals, u32* __restrict__ cursors,
    int* __restrict__ scol, float* __restrict__ sval, int n_edges)
{
    const int e = blockIdx.x * 256 + threadIdx.x;
    if (e >= n_edges) return;
    const u32 p = atomicAdd(&cursors[rows[e]], 1u);
    scol[p] = cols[e];
    sval[p] = vals[e];
}

// ---------------------------------------------------------------------------
// Aggregate: one wave per row. lane j = feature j. acc = bias[j] + sum over
// the row's edges of v * sp[c][j] (coalesced 256B gather/edge). No atomics.
// ---------------------------------------------------------------------------
__global__ __launch_bounds__(256) void aggregate(
    const int* __restrict__ scol, const float* __restrict__ sval,
    const u32* __restrict__ offsets, const float* __restrict__ sp,
    const float* __restrict__ bias, float* __restrict__ out, int n_nodes)
{
    const int wid = (blockIdx.x * 256 + threadIdx.x) >> 6;   // row
    const int lane = threadIdx.x & 63;
    if (wid >= n_nodes) return;
    const int beg = __builtin_amdgcn_readfirstlane((int)offsets[wid]);
    const int end = __builtin_amdgcn_readfirstlane((int)offsets[wid + 1]);

    float acc = bias[lane];
    int i = beg;
    for (; i + 1 < end; i += 2) {
        const int   c0 = scol[i],     c1 = scol[i + 1];
        const float v0 = sval[i],     v1 = sval[i + 1];
        const float s0 = sp[(size_t)c0 * OUT_F + lane];
        const float s1 = sp[(size_t)c1 * OUT_F + lane];
        acc += v0 * s0;
        acc += v1 * s1;
    }
    if (i < end)
        acc += sval[i] * sp[(size_t)scol[i] * OUT_F + lane];
    out[(size_t)wid * OUT_F + lane] = acc;
}

// ---------------------------------------------------------------------------
extern "C" void kernel_launch(void* const* d_in, const int* in_sizes, int n_in,
                              void* d_out, int out_size, void* d_ws, size_t ws_size,
                              hipStream_t stream) {
    const float* x        = (const float*)d_in[0];
    const float* W        = (const float*)d_in[1];
    const float* bias     = (const float*)d_in[2];
    const int*   adj_rows = (const int*)d_in[3];
    const int*   adj_cols = (const int*)d_in[4];
    const float* adj_vals = (const float*)d_in[5];
    float* out = (float*)d_out;

    const int n_nodes = in_sizes[0] / IN_F;
    const int n_edges = in_sizes[3];

    // Workspace layout (4B aligned), ~33.2 MB total:
    char* ws = (char*)d_ws;
    float* sp       = (float*)ws;                                   // n_nodes*64 f32
    u32*   counts   = (u32*)(ws + (size_t)n_nodes * OUT_F * 4);     // n_nodes
    u32*   offsets  = counts + n_nodes;                             // n_nodes+1
    u32*   cursors  = offsets + n_nodes + 1;                        // n_nodes
    u32*   blockSums= cursors + n_nodes;                            // <=256
    int*   scol     = (int*)(blockSums + 256);                      // n_edges
    float* sval     = (float*)(scol + n_edges);                     // n_edges

    // 1) sp = x @ W
    gemm_xw<<<(n_nodes + 63) / 64, 256, 0, stream>>>(x, W, sp, n_nodes);

    // 2) counting sort by row
    hipMemsetAsync(counts, 0, (size_t)n_nodes * 4, stream);
    hist_rows<<<(n_edges + 255) / 256, 256, 0, stream>>>(adj_rows, counts, n_edges);
    const int nb = (n_nodes + 2047) / 2048;
    scan1<<<nb, 256, 0, stream>>>(counts, offsets, blockSums, n_nodes);
    scan2<<<1, 256, 0, stream>>>(blockSums, nb);
    scan3<<<(n_nodes + 1 + 255) / 256, 256, 0, stream>>>(offsets, blockSums, cursors,
                                                         n_nodes, n_edges);
    sort_scatter<<<(n_edges + 255) / 256, 256, 0, stream>>>(
        adj_rows, adj_cols, adj_vals, cursors, scol, sval, n_edges);

    // 3) per-row gather-aggregate (bias folded in, no atomics)
    aggregate<<<(n_nodes + 3) / 4, 256, 0, stream>>>(
        scol, sval, offsets, sp, bias, out, n_nodes);
}

// Round 6
// 1175.876 us; speedup vs baseline: 1.0224x; 1.0224x over previous
//
#include <hip/hip_runtime.h>

#define IN_F 128
#define OUT_F 64
typedef unsigned int u32;

// ---------------------------------------------------------------------------
// Kernel 1: sp = x @ W. 64x64 tile per block (256 thr), 4 rows x 4 cols per
// thread. Accumulators are EXPLICIT named float4s (no address-taking, no
// runtime-selected pointers) so they live in VGPRs — the round-5 version
// spilled 3 GB of scratch via a ternary pointer select.
// ---------------------------------------------------------------------------
__global__ __launch_bounds__(256, 2) void gemm_xw(
    const float* __restrict__ x, const float* __restrict__ W,
    float* __restrict__ sp, int n_nodes)
{
    __shared__ float Wlds[IN_F * OUT_F];     // 32 KB, [k][j]
    __shared__ float xlds[64][IN_F + 4];     // 33.8 KB, stride 132 (pad)

    const int t = threadIdx.x;
    const int row0 = blockIdx.x * 64;

    // W: 8192 floats, 8 float4/thread, coalesced, linear LDS.
    #pragma unroll
    for (int j = 0; j < 8; ++j) {
        const int off = j * 1024 + t * 4;
        *(float4*)&Wlds[off] = *(const float4*)&W[off];
    }
    // x tile: 64 rows x 128 floats contiguous at x + row0*128.
    #pragma unroll
    for (int j = 0; j < 8; ++j) {
        const int off = j * 1024 + t * 4;
        const int r = off >> 7, k = off & 127;
        if (row0 + r < n_nodes)
            *(float4*)&xlds[r][k] = *(const float4*)&x[(size_t)row0 * IN_F + off];
    }
    __syncthreads();

    const int ty = t >> 4;          // 0..15 -> rows ty*4 .. ty*4+3
    const int tx = (t & 15) * 4;    // feature group

    float4 a0 = {0,0,0,0};
    float4 a1 = {0,0,0,0};
    float4 a2 = {0,0,0,0};
    float4 a3 = {0,0,0,0};

    #pragma unroll
    for (int k = 0; k < IN_F; k += 4) {
        const float4 w0 = *(const float4*)&Wlds[(k + 0) * OUT_F + tx];
        const float4 w1 = *(const float4*)&Wlds[(k + 1) * OUT_F + tx];
        const float4 w2 = *(const float4*)&Wlds[(k + 2) * OUT_F + tx];
        const float4 w3 = *(const float4*)&Wlds[(k + 3) * OUT_F + tx];
        const float4 x0 = *(const float4*)&xlds[ty * 4 + 0][k];
        const float4 x1 = *(const float4*)&xlds[ty * 4 + 1][k];
        const float4 x2 = *(const float4*)&xlds[ty * 4 + 2][k];
        const float4 x3 = *(const float4*)&xlds[ty * 4 + 3][k];

        a0.x += x0.x*w0.x + x0.y*w1.x + x0.z*w2.x + x0.w*w3.x;
        a0.y += x0.x*w0.y + x0.y*w1.y + x0.z*w2.y + x0.w*w3.y;
        a0.z += x0.x*w0.z + x0.y*w1.z + x0.z*w2.z + x0.w*w3.z;
        a0.w += x0.x*w0.w + x0.y*w1.w + x0.z*w2.w + x0.w*w3.w;

        a1.x += x1.x*w0.x + x1.y*w1.x + x1.z*w2.x + x1.w*w3.x;
        a1.y += x1.x*w0.y + x1.y*w1.y + x1.z*w2.y + x1.w*w3.y;
        a1.z += x1.x*w0.z + x1.y*w1.z + x1.z*w2.z + x1.w*w3.z;
        a1.w += x1.x*w0.w + x1.y*w1.w + x1.z*w2.w + x1.w*w3.w;

        a2.x += x2.x*w0.x + x2.y*w1.x + x2.z*w2.x + x2.w*w3.x;
        a2.y += x2.x*w0.y + x2.y*w1.y + x2.z*w2.y + x2.w*w3.y;
        a2.z += x2.x*w0.z + x2.y*w1.z + x2.z*w2.z + x2.w*w3.z;
        a2.w += x2.x*w0.w + x2.y*w1.w + x2.z*w2.w + x2.w*w3.w;

        a3.x += x3.x*w0.x + x3.y*w1.x + x3.z*w2.x + x3.w*w3.x;
        a3.y += x3.x*w0.y + x3.y*w1.y + x3.z*w2.y + x3.w*w3.y;
        a3.z += x3.x*w0.z + x3.y*w1.z + x3.z*w2.z + x3.w*w3.z;
        a3.w += x3.x*w0.w + x3.y*w1.w + x3.z*w2.w + x3.w*w3.w;
    }

    const int rowBase = row0 + ty * 4;
    if (rowBase + 0 < n_nodes) *(float4*)&sp[(size_t)(rowBase + 0) * OUT_F + tx] = a0;
    if (rowBase + 1 < n_nodes) *(float4*)&sp[(size_t)(rowBase + 1) * OUT_F + tx] = a1;
    if (rowBase + 2 < n_nodes) *(float4*)&sp[(size_t)(rowBase + 2) * OUT_F + tx] = a2;
    if (rowBase + 3 < n_nodes) *(float4*)&sp[(size_t)(rowBase + 3) * OUT_F + tx] = a3;
}

// ---------------------------------------------------------------------------
// Counting sort of edges by row: hist -> scan (3 kernels) -> scatter.
// ---------------------------------------------------------------------------
__global__ __launch_bounds__(256) void hist_rows(
    const int* __restrict__ rows, u32* __restrict__ counts, int n_edges)
{
    const int e = blockIdx.x * 256 + threadIdx.x;
    if (e < n_edges) atomicAdd(&counts[rows[e]], 1u);
}

// scan1: per-block (2048 elems) exclusive partials + block sums
__global__ __launch_bounds__(256) void scan1(
    const u32* __restrict__ counts, u32* __restrict__ partial,
    u32* __restrict__ blockSums, int n)
{
    __shared__ u32 sdata[256];
    const int t = threadIdx.x;
    const int base = blockIdx.x * 2048 + t * 8;
    u32 v[8], s = 0;
    #pragma unroll
    for (int j = 0; j < 8; ++j) { v[j] = (base + j < n) ? counts[base + j] : 0u; s += v[j]; }
    sdata[t] = s;
    __syncthreads();
    for (int off = 1; off < 256; off <<= 1) {
        u32 xv = (t >= off) ? sdata[t - off] : 0u;
        __syncthreads();
        sdata[t] += xv;
        __syncthreads();
    }
    const u32 excl = sdata[t] - s;
    if (t == 255) blockSums[blockIdx.x] = sdata[255];
    u32 run = excl;
    #pragma unroll
    for (int j = 0; j < 8; ++j) { if (base + j < n) partial[base + j] = run; run += v[j]; }
}

// scan2: single block, exclusive scan of block sums (in place)
__global__ __launch_bounds__(256) void scan2(u32* __restrict__ blockSums, int nb)
{
    __shared__ u32 sdata[256];
    const int t = threadIdx.x;
    const u32 v = (t < nb) ? blockSums[t] : 0u;
    sdata[t] = v;
    __syncthreads();
    for (int off = 1; off < 256; off <<= 1) {
        u32 xv = (t >= off) ? sdata[t - off] : 0u;
        __syncthreads();
        sdata[t] += xv;
        __syncthreads();
    }
    if (t < nb) blockSums[t] = sdata[t] - v;
}

// scan3: add block offsets; produce final offsets + cursor copy; offsets[n]=E
__global__ __launch_bounds__(256) void scan3(
    u32* __restrict__ offsets, const u32* __restrict__ blockSums,
    u32* __restrict__ cursors, int n, int total)
{
    const int i = blockIdx.x * 256 + threadIdx.x;
    if (i < n) {
        const u32 o = offsets[i] + blockSums[i >> 11];
        offsets[i] = o;
        cursors[i] = o;
    }
    if (i == n) offsets[n] = (u32)total;
}

__global__ __launch_bounds__(256) void sort_scatter(
    const int* __restrict__ rows, const int* __restrict__ cols,
    const float* __restrict__ vals, u32* __restrict__ cursors,
    int* __restrict__ scol, float* __restrict__ sval, int n_edges)
{
    const int e = blockIdx.x * 256 + threadIdx.x;
    if (e >= n_edges) return;
    const u32 p = atomicAdd(&cursors[rows[e]], 1u);
    scol[p] = cols[e];
    sval[p] = vals[e];
}

// ---------------------------------------------------------------------------
// Aggregate: one wave per row. lane j = feature j. acc = bias[j] + sum over
// the row's edges of v * sp[c][j] (coalesced 256B gather/edge). No atomics.
// ---------------------------------------------------------------------------
__global__ __launch_bounds__(256) void aggregate(
    const int* __restrict__ scol, const float* __restrict__ sval,
    const u32* __restrict__ offsets, const float* __restrict__ sp,
    const float* __restrict__ bias, float* __restrict__ out, int n_nodes)
{
    const int wid = (blockIdx.x * 256 + threadIdx.x) >> 6;   // row
    const int lane = threadIdx.x & 63;
    if (wid >= n_nodes) return;
    const int beg = __builtin_amdgcn_readfirstlane((int)offsets[wid]);
    const int end = __builtin_amdgcn_readfirstlane((int)offsets[wid + 1]);

    float acc = bias[lane];
    int i = beg;
    for (; i + 1 < end; i += 2) {
        const int   c0 = scol[i],     c1 = scol[i + 1];
        const float v0 = sval[i],     v1 = sval[i + 1];
        const float s0 = sp[(size_t)c0 * OUT_F + lane];
        const float s1 = sp[(size_t)c1 * OUT_F + lane];
        acc += v0 * s0;
        acc += v1 * s1;
    }
    if (i < end)
        acc += sval[i] * sp[(size_t)scol[i] * OUT_F + lane];
    out[(size_t)wid * OUT_F + lane] = acc;
}

// ---------------------------------------------------------------------------
extern "C" void kernel_launch(void* const* d_in, const int* in_sizes, int n_in,
                              void* d_out, int out_size, void* d_ws, size_t ws_size,
                              hipStream_t stream) {
    const float* x        = (const float*)d_in[0];
    const float* W        = (const float*)d_in[1];
    const float* bias     = (const float*)d_in[2];
    const int*   adj_rows = (const int*)d_in[3];
    const int*   adj_cols = (const int*)d_in[4];
    const float* adj_vals = (const float*)d_in[5];
    float* out = (float*)d_out;

    const int n_nodes = in_sizes[0] / IN_F;
    const int n_edges = in_sizes[3];

    // Workspace layout (4B aligned), ~33.2 MB total:
    char* ws = (char*)d_ws;
    float* sp       = (float*)ws;                                   // n_nodes*64 f32
    u32*   counts   = (u32*)(ws + (size_t)n_nodes * OUT_F * 4);     // n_nodes
    u32*   offsets  = counts + n_nodes;                             // n_nodes+1
    u32*   cursors  = offsets + n_nodes + 1;                        // n_nodes
    u32*   blockSums= cursors + n_nodes;                            // <=256
    int*   scol     = (int*)(blockSums + 256);                      // n_edges
    float* sval     = (float*)(scol + n_edges);                     // n_edges

    // 1) sp = x @ W
    gemm_xw<<<(n_nodes + 63) / 64, 256, 0, stream>>>(x, W, sp, n_nodes);

    // 2) counting sort by row
    hipMemsetAsync(counts, 0, (size_t)n_nodes * 4, stream);
    hist_rows<<<(n_edges + 255) / 256, 256, 0, stream>>>(adj_rows, counts, n_edges);
    const int nb = (n_nodes + 2047) / 2048;
    scan1<<<nb, 256, 0, stream>>>(counts, offsets, blockSums, n_nodes);
    scan2<<<1, 256, 0, stream>>>(blockSums, nb);
    scan3<<<(n_nodes + 1 + 255) / 256, 256, 0, stream>>>(offsets, blockSums, cursors,
                                                         n_nodes, n_edges);
    sort_scatter<<<(n_edges + 255) / 256, 256, 0, stream>>>(
        adj_rows, adj_cols, adj_vals, cursors, scol, sval, n_edges);

    // 3) per-row gather-aggregate (bias folded in, no atomics)
    aggregate<<<(n_nodes + 3) / 4, 256, 0, stream>>>(
        scol, sval, offsets, sp, bias, out, n_nodes);
}

// Round 7
// 260.573 us; speedup vs baseline: 4.6136x; 4.5127x over previous
//
#include <hip/hip_runtime.h>

#define IN_F 128
#define OUT_F 64
typedef unsigned int u32;

// ---------------------------------------------------------------------------
// Kernel 1: sp = x @ W. 64x64 tile per block (256 thr), 4 rows x 4 cols per
// thread. k-loop unroll is CAPPED at 2: full unroll hoisted all 256 LDS
// float4 loads ahead of use, spilled ~4KB/thread to scratch -> 2.9 GB HBM
// (rounds 5/6). With unroll 2, live set ~96 VGPRs -> no spill.
// ---------------------------------------------------------------------------
__global__ __launch_bounds__(256, 2) void gemm_xw(
    const float* __restrict__ x, const float* __restrict__ W,
    float* __restrict__ sp, int n_nodes)
{
    __shared__ float Wlds[IN_F * OUT_F];     // 32 KB, [k][j]
    __shared__ float xlds[64][IN_F + 4];     // 33.8 KB, stride 132 (pad)

    const int t = threadIdx.x;
    const int row0 = blockIdx.x * 64;

    // W: 8192 floats, 8 float4/thread, coalesced, linear LDS.
    #pragma unroll
    for (int j = 0; j < 8; ++j) {
        const int off = j * 1024 + t * 4;
        *(float4*)&Wlds[off] = *(const float4*)&W[off];
    }
    // x tile: 64 rows x 128 floats contiguous at x + row0*128.
    #pragma unroll
    for (int j = 0; j < 8; ++j) {
        const int off = j * 1024 + t * 4;
        const int r = off >> 7, k = off & 127;
        if (row0 + r < n_nodes)
            *(float4*)&xlds[r][k] = *(const float4*)&x[(size_t)row0 * IN_F + off];
    }
    __syncthreads();

    const int ty = t >> 4;          // 0..15 -> rows ty*4 .. ty*4+3
    const int tx = (t & 15) * 4;    // feature group

    float4 a0 = {0,0,0,0};
    float4 a1 = {0,0,0,0};
    float4 a2 = {0,0,0,0};
    float4 a3 = {0,0,0,0};

    #pragma unroll 2
    for (int k = 0; k < IN_F; k += 4) {
        const float4 w0 = *(const float4*)&Wlds[(k + 0) * OUT_F + tx];
        const float4 w1 = *(const float4*)&Wlds[(k + 1) * OUT_F + tx];
        const float4 w2 = *(const float4*)&Wlds[(k + 2) * OUT_F + tx];
        const float4 w3 = *(const float4*)&Wlds[(k + 3) * OUT_F + tx];
        const float4 x0 = *(const float4*)&xlds[ty * 4 + 0][k];
        const float4 x1 = *(const float4*)&xlds[ty * 4 + 1][k];
        const float4 x2 = *(const float4*)&xlds[ty * 4 + 2][k];
        const float4 x3 = *(const float4*)&xlds[ty * 4 + 3][k];

        a0.x += x0.x*w0.x + x0.y*w1.x + x0.z*w2.x + x0.w*w3.x;
        a0.y += x0.x*w0.y + x0.y*w1.y + x0.z*w2.y + x0.w*w3.y;
        a0.z += x0.x*w0.z + x0.y*w1.z + x0.z*w2.z + x0.w*w3.z;
        a0.w += x0.x*w0.w + x0.y*w1.w + x0.z*w2.w + x0.w*w3.w;

        a1.x += x1.x*w0.x + x1.y*w1.x + x1.z*w2.x + x1.w*w3.x;
        a1.y += x1.x*w0.y + x1.y*w1.y + x1.z*w2.y + x1.w*w3.y;
        a1.z += x1.x*w0.z + x1.y*w1.z + x1.z*w2.z + x1.w*w3.z;
        a1.w += x1.x*w0.w + x1.y*w1.w + x1.z*w2.w + x1.w*w3.w;

        a2.x += x2.x*w0.x + x2.y*w1.x + x2.z*w2.x + x2.w*w3.x;
        a2.y += x2.x*w0.y + x2.y*w1.y + x2.z*w2.y + x2.w*w3.y;
        a2.z += x2.x*w0.z + x2.y*w1.z + x2.z*w2.z + x2.w*w3.z;
        a2.w += x2.x*w0.w + x2.y*w1.w + x2.z*w2.w + x2.w*w3.w;

        a3.x += x3.x*w0.x + x3.y*w1.x + x3.z*w2.x + x3.w*w3.x;
        a3.y += x3.x*w0.y + x3.y*w1.y + x3.z*w2.y + x3.w*w3.y;
        a3.z += x3.x*w0.z + x3.y*w1.z + x3.z*w2.z + x3.w*w3.z;
        a3.w += x3.x*w0.w + x3.y*w1.w + x3.z*w2.w + x3.w*w3.w;
    }

    const int rowBase = row0 + ty * 4;
    if (rowBase + 0 < n_nodes) *(float4*)&sp[(size_t)(rowBase + 0) * OUT_F + tx] = a0;
    if (rowBase + 1 < n_nodes) *(float4*)&sp[(size_t)(rowBase + 1) * OUT_F + tx] = a1;
    if (rowBase + 2 < n_nodes) *(float4*)&sp[(size_t)(rowBase + 2) * OUT_F + tx] = a2;
    if (rowBase + 3 < n_nodes) *(float4*)&sp[(size_t)(rowBase + 3) * OUT_F + tx] = a3;
}

// ---------------------------------------------------------------------------
// Counting sort of edges by row: hist -> scan (3 kernels) -> scatter.
// ---------------------------------------------------------------------------
__global__ __launch_bounds__(256) void hist_rows(
    const int* __restrict__ rows, u32* __restrict__ counts, int n_edges)
{
    const int e = blockIdx.x * 256 + threadIdx.x;
    if (e < n_edges) atomicAdd(&counts[rows[e]], 1u);
}

// scan1: per-block (2048 elems) exclusive partials + block sums
__global__ __launch_bounds__(256) void scan1(
    const u32* __restrict__ counts, u32* __restrict__ partial,
    u32* __restrict__ blockSums, int n)
{
    __shared__ u32 sdata[256];
    const int t = threadIdx.x;
    const int base = blockIdx.x * 2048 + t * 8;
    u32 v[8], s = 0;
    #pragma unroll
    for (int j = 0; j < 8; ++j) { v[j] = (base + j < n) ? counts[base + j] : 0u; s += v[j]; }
    sdata[t] = s;
    __syncthreads();
    for (int off = 1; off < 256; off <<= 1) {
        u32 xv = (t >= off) ? sdata[t - off] : 0u;
        __syncthreads();
        sdata[t] += xv;
        __syncthreads();
    }
    const u32 excl = sdata[t] - s;
    if (t == 255) blockSums[blockIdx.x] = sdata[255];
    u32 run = excl;
    #pragma unroll
    for (int j = 0; j < 8; ++j) { if (base + j < n) partial[base + j] = run; run += v[j]; }
}

// scan2: single block, exclusive scan of block sums (in place)
__global__ __launch_bounds__(256) void scan2(u32* __restrict__ blockSums, int nb)
{
    __shared__ u32 sdata[256];
    const int t = threadIdx.x;
    const u32 v = (t < nb) ? blockSums[t] : 0u;
    sdata[t] = v;
    __syncthreads();
    for (int off = 1; off < 256; off <<= 1) {
        u32 xv = (t >= off) ? sdata[t - off] : 0u;
        __syncthreads();
        sdata[t] += xv;
        __syncthreads();
    }
    if (t < nb) blockSums[t] = sdata[t] - v;
}

// scan3: add block offsets; produce final offsets + cursor copy; offsets[n]=E
__global__ __launch_bounds__(256) void scan3(
    u32* __restrict__ offsets, const u32* __restrict__ blockSums,
    u32* __restrict__ cursors, int n, int total)
{
    const int i = blockIdx.x * 256 + threadIdx.x;
    if (i < n) {
        const u32 o = offsets[i] + blockSums[i >> 11];
        offsets[i] = o;
        cursors[i] = o;
    }
    if (i == n) offsets[n] = (u32)total;
}

__global__ __launch_bounds__(256) void sort_scatter(
    const int* __restrict__ rows, const int* __restrict__ cols,
    const float* __restrict__ vals, u32* __restrict__ cursors,
    int* __restrict__ scol, float* __restrict__ sval, int n_edges)
{
    const int e = blockIdx.x * 256 + threadIdx.x;
    if (e >= n_edges) return;
    const u32 p = atomicAdd(&cursors[rows[e]], 1u);
    scol[p] = cols[e];
    sval[p] = vals[e];
}

// ---------------------------------------------------------------------------
// Aggregate: one wave per row. lane j = feature j. acc = bias[j] + sum over
// the row's edges of v * sp[c][j] (coalesced 256B gather/edge). No atomics.
// ---------------------------------------------------------------------------
__global__ __launch_bounds__(256) void aggregate(
    const int* __restrict__ scol, const float* __restrict__ sval,
    const u32* __restrict__ offsets, const float* __restrict__ sp,
    const float* __restrict__ bias, float* __restrict__ out, int n_nodes)
{
    const int wid = (blockIdx.x * 256 + threadIdx.x) >> 6;   // row
    const int lane = threadIdx.x & 63;
    if (wid >= n_nodes) return;
    const int beg = __builtin_amdgcn_readfirstlane((int)offsets[wid]);
    const int end = __builtin_amdgcn_readfirstlane((int)offsets[wid + 1]);

    float acc = bias[lane];
    int i = beg;
    for (; i + 1 < end; i += 2) {
        const int   c0 = scol[i],     c1 = scol[i + 1];
        const float v0 = sval[i],     v1 = sval[i + 1];
        const float s0 = sp[(size_t)c0 * OUT_F + lane];
        const float s1 = sp[(size_t)c1 * OUT_F + lane];
        acc += v0 * s0;
        acc += v1 * s1;
    }
    if (i < end)
        acc += sval[i] * sp[(size_t)scol[i] * OUT_F + lane];
    out[(size_t)wid * OUT_F + lane] = acc;
}

// ---------------------------------------------------------------------------
extern "C" void kernel_launch(void* const* d_in, const int* in_sizes, int n_in,
                              void* d_out, int out_size, void* d_ws, size_t ws_size,
                              hipStream_t stream) {
    const float* x        = (const float*)d_in[0];
    const float* W        = (const float*)d_in[1];
    const float* bias     = (const float*)d_in[2];
    const int*   adj_rows = (const int*)d_in[3];
    const int*   adj_cols = (const int*)d_in[4];
    const float* adj_vals = (const float*)d_in[5];
    float* out = (float*)d_out;

    const int n_nodes = in_sizes[0] / IN_F;
    const int n_edges = in_sizes[3];

    // Workspace layout (4B aligned), ~33.2 MB total:
    char* ws = (char*)d_ws;
    float* sp       = (float*)ws;                                   // n_nodes*64 f32
    u32*   counts   = (u32*)(ws + (size_t)n_nodes * OUT_F * 4);     // n_nodes
    u32*   offsets  = counts + n_nodes;                             // n_nodes+1
    u32*   cursors  = offsets + n_nodes + 1;                        // n_nodes
    u32*   blockSums= cursors + n_nodes;                            // <=256
    int*   scol     = (int*)(blockSums + 256);                      // n_edges
    float* sval     = (float*)(scol + n_edges);                     // n_edges

    // 1) sp = x @ W
    gemm_xw<<<(n_nodes + 63) / 64, 256, 0, stream>>>(x, W, sp, n_nodes);

    // 2) counting sort by row
    hipMemsetAsync(counts, 0, (size_t)n_nodes * 4, stream);
    hist_rows<<<(n_edges + 255) / 256, 256, 0, stream>>>(adj_rows, counts, n_edges);
    const int nb = (n_nodes + 2047) / 2048;
    scan1<<<nb, 256, 0, stream>>>(counts, offsets, blockSums, n_nodes);
    scan2<<<1, 256, 0, stream>>>(blockSums, nb);
    scan3<<<(n_nodes + 1 + 255) / 256, 256, 0, stream>>>(offsets, blockSums, cursors,
                                                         n_nodes, n_edges);
    sort_scatter<<<(n_edges + 255) / 256, 256, 0, stream>>>(
        adj_rows, adj_cols, adj_vals, cursors, scol, sval, n_edges);

    // 3) per-row gather-aggregate (bias folded in, no atomics)
    aggregate<<<(n_nodes + 3) / 4, 256, 0, stream>>>(
        scol, sval, offsets, sp, bias, out, n_nodes);
}